// Round 17
// baseline (227.283 us; speedup 1.0000x reference)
//
#include <hip/hip_runtime.h>
#include <hip/hip_fp16.h>
#include <stdint.h>

#define DEVI __device__ __forceinline__

using f16x2 = __attribute__((ext_vector_type(2))) _Float16;
using f16x8 = __attribute__((ext_vector_type(8))) _Float16;
using f32x4 = __attribute__((ext_vector_type(4))) float;
using f32x16 = __attribute__((ext_vector_type(16))) float;
using u32x4 = __attribute__((ext_vector_type(4))) uint32_t;

// global -> LDS direct copy, 16B per lane. LDS dest is wave-uniform base;
// HW writes base + lane*16 (guide m104/m108). Global src is per-lane.
DEVI void gload_lds16(const void* g, void* lds) {
  using GP = const __attribute__((address_space(1))) void*;
  using LP = __attribute__((address_space(3))) void*;
  __builtin_amdgcn_global_load_lds((GP)g, (LP)lds, 16, 0, 0);
}

DEVI uint32_t pack2h(float a, float b) {
  return (uint32_t)__half_as_ushort(__float2half(a)) |
         ((uint32_t)__half_as_ushort(__float2half(b)) << 16);
}

DEVI uint32_t cvtpk(float a, float b) {  // v_cvt_pkrtz_f16_f32
  auto h2 = __builtin_amdgcn_cvt_pkrtz(a, b);
  return __builtin_bit_cast(uint32_t, h2);
}

DEVI void plswap(uint32_t& a, uint32_t& b) {  // v_permlane32_swap_b32 (distinct values only)
  asm volatile("v_permlane32_swap_b32 %0, %1" : "+v"(a), "+v"(b));
}

DEVI float dot2acc(uint32_t w, f16x2 one, float c) {  // v_dot2_f32_f16
  return __builtin_amdgcn_fdot2(__builtin_bit_cast(f16x2, w), one, c, false);
}

DEVI float fmax3(float a, float b, float c) { return fmaxf(fmaxf(a, b), c); }

// ---------------- fused f32 -> f16 convert for all three inputs ----------------
// x: 1048576 groups, wqkv: 393216, wout: 131072; total 1572864 = 6144 * 256.
__global__ __launch_bounds__(256) void cvt3_f32_f16(const float* __restrict__ x,
                                                    const float* __restrict__ wq,
                                                    const float* __restrict__ wo,
                                                    __half* __restrict__ xb,
                                                    __half* __restrict__ wqb,
                                                    __half* __restrict__ wob) {
  int i = blockIdx.x * 256 + threadIdx.x;
  const float* in;
  __half* out;
  int j;
  if (i < 1048576) {
    in = x; out = xb; j = i;
  } else if (i < 1048576 + 393216) {
    in = wq; out = wqb; j = i - 1048576;
  } else {
    in = wo; out = wob; j = i - 1441792;
  }
  float4 a = ((const float4*)in)[j * 2];
  float4 b = ((const float4*)in)[j * 2 + 1];
  uint4 u;
  u.x = pack2h(a.x, a.y);
  u.y = pack2h(a.z, a.w);
  u.z = pack2h(b.x, b.y);
  u.w = pack2h(b.z, b.w);
  ((uint4*)out)[j] = u;
}

// ================= shared GEMM core (128x128 tile, BK=64, proven) ==========
#define GEMM_CORE(A_, B_, K_, BX_, BY_)                                                 \
  __shared__ __half As[128 * 64];                                                       \
  __shared__ __half Bs[128 * 64];                                                       \
  const int tid = threadIdx.x;                                                          \
  const int w = tid >> 6, l = tid & 63;                                                 \
  const int wm = w >> 1, wn = w & 1;                                                    \
  const int m16 = l & 15, g = l >> 4;                                                   \
  const int row0 = (BY_)*128, col0 = (BX_)*128;                                         \
  const int srow = l >> 3;                                                              \
  const int ks = ((l & 7) ^ srow) * 8;                                                  \
  f32x4 acc[4][4] = {};                                                                 \
  for (int kt = 0; kt < (K_); kt += 64) {                                               \
    __syncthreads();                                                                    \
    _Pragma("unroll") for (int i = 0; i < 4; ++i) {                                     \
      int c = w * 4 + i;                                                                \
      int r = c * 8 + srow;                                                             \
      gload_lds16((A_) + (size_t)(row0 + r) * (K_) + kt + ks, (char*)As + c * 1024);    \
      gload_lds16((B_) + (size_t)(col0 + r) * (K_) + kt + ks, (char*)Bs + c * 1024);    \
    }                                                                                   \
    __syncthreads();                                                                    \
    _Pragma("unroll") for (int kk = 0; kk < 2; ++kk) {                                  \
      f16x8 aF[4], bF[4];                                                               \
      _Pragma("unroll") for (int mi = 0; mi < 4; ++mi) {                                \
        int r = wm * 64 + mi * 16 + m16;                                                \
        aF[mi] = *(const f16x8*)((const char*)As + r * 128 + (((kk * 4 + g) ^ (r & 7)) << 4)); \
      }                                                                                 \
      _Pragma("unroll") for (int ni = 0; ni < 4; ++ni) {                                \
        int r = wn * 64 + ni * 16 + m16;                                                \
        bF[ni] = *(const f16x8*)((const char*)Bs + r * 128 + (((kk * 4 + g) ^ (r & 7)) << 4)); \
      }                                                                                 \
      _Pragma("unroll") for (int mi = 0; mi < 4; ++mi)                                  \
          _Pragma("unroll") for (int ni = 0; ni < 4; ++ni)                              \
              acc[mi][ni] = __builtin_amdgcn_mfma_f32_16x16x32_f16(aF[mi], bF[ni],      \
                                                                   acc[mi][ni], 0, 0, 0); \
    }                                                                                   \
  }

// ---------------- GEMM + fused RoPE/scatter, 256x128 tile, 512 threads ----------
// R17 bisect: ONLY change vs R14. 8 waves (4M x 2N), same swizzle formulas as the
// proven 128^2 core (row pitch 128B, slot ^= r&7). Staging bytes/MFMA -25%;
// barriers per FLOP halved. Wave still owns exactly one head (wn parity).
__global__ __launch_bounds__(512, 4) void gemm_qkv_rope(const __half* __restrict__ A,
                                                        const __half* __restrict__ B,
                                                        const float* __restrict__ rot,
                                                        __half* __restrict__ qr,
                                                        __half* __restrict__ kr,
                                                        __half* __restrict__ vr) {
  __shared__ __half As[256 * 64];  // 32 KB
  __shared__ __half Bs[128 * 64];  // 16 KB
  const int tid = threadIdx.x;
  const int w = tid >> 6, l = tid & 63;  // w in [0,8)
  const int wm = w >> 1, wn = w & 1;     // wm in [0,4)
  const int m16 = l & 15, g = l >> 4;
  const int id = blockIdx.y * 24 + blockIdx.x;  // 32*24 = 768 blocks
  const int nid = (id & 7) * 96 + (id >> 3);    // XCD swizzle (768 % 8 == 0, bijective)
  const int bx = nid % 24, by = nid / 24;
  const int row0 = by * 256, col0 = bx * 128;
  const int srow = l >> 3;
  const int ks = ((l & 7) ^ srow) * 8;

  f32x4 acc[4][4] = {};

  for (int kt = 0; kt < 1024; kt += 64) {
    __syncthreads();
#pragma unroll
    for (int i = 0; i < 4; ++i) {  // A: 32 chunks of 8 rows (256 rows)
      int c = w * 4 + i;
      int r = c * 8 + srow;
      gload_lds16(A + (size_t)(row0 + r) * 1024 + kt + ks, (char*)As + c * 1024);
    }
#pragma unroll
    for (int i = 0; i < 2; ++i) {  // B: 16 chunks of 8 rows (128 rows)
      int c = w * 2 + i;
      int r = c * 8 + srow;
      gload_lds16(B + (size_t)(col0 + r) * 1024 + kt + ks, (char*)Bs + c * 1024);
    }
    __syncthreads();
#pragma unroll
    for (int kk = 0; kk < 2; ++kk) {
      f16x8 aF[4], bF[4];
#pragma unroll
      for (int mi = 0; mi < 4; ++mi) {
        int r = wm * 64 + mi * 16 + m16;
        aF[mi] = *(const f16x8*)((const char*)As + r * 128 + (((kk * 4 + g) ^ (r & 7)) << 4));
      }
#pragma unroll
      for (int ni = 0; ni < 4; ++ni) {
        int r = wn * 64 + ni * 16 + m16;
        bF[ni] = *(const f16x8*)((const char*)Bs + r * 128 + (((kk * 4 + g) ^ (r & 7)) << 4));
      }
#pragma unroll
      for (int mi = 0; mi < 4; ++mi)
#pragma unroll
        for (int ni = 0; ni < 4; ++ni)
          acc[mi][ni] = __builtin_amdgcn_mfma_f32_16x16x32_f16(aF[mi], bF[ni], acc[mi][ni], 0, 0, 0);
    }
  }

  const int s = bx >> 3;                 // 0=q, 1=k, 2=v
  const int hh = (bx & 7) * 2 + wn;      // this wave's head
  if (s < 2) {
    const float sc = (s == 0) ? 0.18033688011112042f : 1.0f;  // log2(e)/sqrt(64)
    __half* base = (s == 0) ? qr : kr;
#pragma unroll
    for (int mi = 0; mi < 4; ++mi)
#pragma unroll
      for (int j = 0; j < 4; ++j) {
        int r = row0 + wm * 64 + mi * 16 + g * 4 + j;  // global row = b*2048+n
        int n = r & 2047;
        int bh = (r >> 11) * 16 + hh;
        __half* orow = base + ((size_t)bh * 2048 + n) * 64;
        const float* rp = rot + n * 64;
#pragma unroll
        for (int ni = 0; ni < 2; ++ni) {
          int dlo = ni * 16 + m16;
          float xlo = acc[mi][ni][j], xhi = acc[mi][ni + 2][j];
          float s0, c0, s1, c1;
          __sincosf(rp[dlo], &s0, &c0);
          __sincosf(rp[dlo + 32], &s1, &c1);
          orow[dlo]      = __float2half((xlo * c0 - xhi * s0) * sc);
          orow[dlo + 32] = __float2half((xhi * c1 + xlo * s1) * sc);
        }
      }
  } else {
#pragma unroll
    for (int mi = 0; mi < 4; ++mi)
#pragma unroll
      for (int j = 0; j < 4; ++j) {
        int r = row0 + wm * 64 + mi * 16 + g * 4 + j;
        int n = r & 2047;
        int bh = (r >> 11) * 16 + hh;
        __half* vcol = vr + ((size_t)bh * 64) * 2048 + n;
#pragma unroll
        for (int ni = 0; ni < 4; ++ni) {
          int d = ni * 16 + m16;
          vcol[(size_t)d * 2048] = __float2half(acc[mi][ni][j]);
        }
      }
  }
}

// ---------------- plain GEMM (out-proj), 128x128, f32 output, XCD-swizzled --------
__global__ __launch_bounds__(256) void gemm_bt_f32(const __half* __restrict__ A,
                                                   const __half* __restrict__ B,
                                                   float* __restrict__ C, int N, int K) {
  const int id = blockIdx.y * 8 + blockIdx.x;         // 512 blocks
  const int nid = (id & 7) * 64 + (id >> 3);          // XCD swizzle (bijective)
  const int bx = nid % 8, by = nid / 8;

  GEMM_CORE(A, B, K, bx, by)
#pragma unroll
  for (int mi = 0; mi < 4; ++mi)
#pragma unroll
    for (int ni = 0; ni < 4; ++ni)
#pragma unroll
      for (int j = 0; j < 4; ++j) {
        int r = row0 + wm * 64 + mi * 16 + g * 4 + j;
        int cc = col0 + wn * 64 + ni * 16 + m16;
        C[(size_t)r * N + cc] = acc[mi][ni][j];
      }
}

// ---------------- Flash attention fwd, swapped-QK 32x32 (EXACT R14 version) --------
__global__ __launch_bounds__(256, 4) void attn_fwd(const __half* __restrict__ qr,
                                                   const __half* __restrict__ kr,
                                                   const __half* __restrict__ vr,
                                                   __half* __restrict__ out) {
  __shared__ __half K2[2 * 64 * 64];  // 16 KB
  __shared__ __half V2[2 * 64 * 64];  // 16 KB

  int bid = blockIdx.x;
  bid = (bid & 7) * 128 + (bid >> 3);  // XCD swizzle: same-head blocks share an XCD L2
  const int bh = bid >> 4;
  const int q0 = (bid & 15) * 128;
  const int tid = threadIdx.x;
  const int w = tid >> 6, l = tid & 63;
  const int q = l & 31, hi = l >> 5;
  const size_t headoff = (size_t)bh * 2048 * 64;

  // Q B-frags: Q[q0+w*32+q][c*16 + hi*8 .. +7], c=0..3 (held all block)
  f16x8 qB[4];
  {
    const __half* qp = qr + headoff + (size_t)(q0 + w * 32 + q) * 64 + hi * 8;
#pragma unroll
    for (int c = 0; c < 4; ++c) qB[c] = *(const f16x8*)(qp + c * 16);
  }

  // hoisted lane-invariant LDS read offsets
  int kf[4];  // K A-frag: byte = Kb + kvb*4096 + kf[c]   (kvb in {0,1})
#pragma unroll
  for (int c = 0; c < 4; ++c)
    kf[c] = q * 128 + 16 * (hi ^ (q & 1)) + 32 * (c ^ ((q >> 1) & 3));
  // V B-frag: byte = Vb + (vbase ^ (kvb<<6) [^32 hi16]) [+4096 for d1]
  const int vbase = q * 128 + ((hi ^ (q & 7)) << 4);

  // staging coords
  const int krow_l = l >> 3, kslot = l & 7;
  const __half* kb = kr + headoff;
  const __half* vb = vr + (size_t)bh * 64 * 2048;

  auto STAGE = [&](int buf, int kv0) {
#pragma unroll
    for (int i = 0; i < 2; ++i) {  // K [64 kv][64 d], slot ^= kv&7
      int c = w * 2 + i;
      int row = c * 8 + krow_l;
      gload_lds16(kb + (size_t)(kv0 + row) * 64 + ((kslot ^ (row & 7)) * 8),
                  (char*)K2 + buf * 8192 + c * 1024);
    }
#pragma unroll
    for (int i = 0; i < 2; ++i) {  // V [64 d][64 kv], slot ^= d&7
      int c = w * 2 + i;
      int d = c * 8 + (l >> 3);
      gload_lds16(vb + (size_t)d * 2048 + kv0 + (((l & 7) ^ (l >> 3)) * 8),
                  (char*)V2 + buf * 8192 + c * 1024);
    }
  };

  const f16x2 one2 = {(_Float16)1.f, (_Float16)1.f};
  f32x16 o0 = {}, o1 = {};  // O[q-rows][d0=q / d1=q+32]
  float mreg = -1e30f, lreg = 0.f;

  STAGE(0, 0);
  __syncthreads();

  for (int t = 0; t < 32; ++t) {
    const int buf = t & 1;
    if (t < 31) STAGE(buf ^ 1, (t + 1) * 64);  // prefetch next tile (overlaps compute)

    const char* Kb = (const char*)K2 + buf * 8192;
    const char* Vb = (const char*)V2 + buf * 8192;
#pragma unroll
    for (int kvb = 0; kvb < 2; ++kvb) {
      // ---- S^T[kv 32][q 32] = K * Q^T
      f32x16 s = {};
      __builtin_amdgcn_s_setprio(1);
#pragma unroll
      for (int c = 0; c < 4; ++c) {
        f16x8 kA = *(const f16x8*)(Kb + kvb * 4096 + kf[c]);
        s = __builtin_amdgcn_mfma_f32_32x32x16_f16(kA, qB[c], s, 0, 0, 0);
      }
      __builtin_amdgcn_s_setprio(0);

      // ---- in-register online softmax (lane owns q-col l&31, 16 kv rows)
      float mt = fmax3(s[0], s[1], s[2]);
      mt = fmax3(mt, s[3], s[4]);
      mt = fmax3(mt, s[5], s[6]);
      mt = fmax3(mt, s[7], s[8]);
      mt = fmax3(mt, s[9], s[10]);
      mt = fmax3(mt, s[11], s[12]);
      mt = fmax3(mt, s[13], s[14]);
      mt = fmaxf(mt, s[15]);
      mt = fmaxf(mt, __shfl_xor(mt, 32));
      if (__any(mt - mreg > 8.f)) {  // defer-max (T13)
        float mnew = fmaxf(mreg, mt);
        float alpha = __builtin_amdgcn_exp2f(mreg - mnew);
        lreg *= alpha;
        o0 *= alpha;
        o1 *= alpha;
        mreg = mnew;
      }
      uint32_t W[8];
      float rs = 0.f;
#pragma unroll
      for (int i2 = 0; i2 < 8; ++i2) {  // exp2 + pack + fused row-sum (fdot2)
        float e0 = __builtin_amdgcn_exp2f(s[2 * i2] - mreg);
        float e1 = __builtin_amdgcn_exp2f(s[2 * i2 + 1] - mreg);
        W[i2] = cvtpk(e0, e1);
        rs = dot2acc(W[i2], one2, rs);
      }
      rs += __shfl_xor(rs, 32);
      lreg += rs;

      // ---- P-frag redistribution: 4 permlane32_swap (proven)
      plswap(W[0], W[2]);
      plswap(W[1], W[3]);
      plswap(W[4], W[6]);
      plswap(W[5], W[7]);
      u32x4 f0 = {W[0], W[1], W[2], W[3]};
      u32x4 f1 = {W[4], W[5], W[6], W[7]};
      f16x8 pA0 = __builtin_bit_cast(f16x8, f0);  // kv kvb*32 + 0..15
      f16x8 pA1 = __builtin_bit_cast(f16x8, f1);  // kv kvb*32 + 16..31

      // ---- PV: O += P * V   (V reads from 128B-row layout)
      const int vx = vbase ^ (kvb << 6);   // kv lo-16 slot
      const int vx2 = vx ^ 32;             // kv hi-16 slot
      f16x8 v00 = *(const f16x8*)(Vb + vx);
      f16x8 v01 = *(const f16x8*)(Vb + vx + 4096);
      f16x8 v10 = *(const f16x8*)(Vb + vx2);
      f16x8 v11 = *(const f16x8*)(Vb + vx2 + 4096);
      __builtin_amdgcn_s_setprio(1);
      o0 = __builtin_amdgcn_mfma_f32_32x32x16_f16(pA0, v00, o0, 0, 0, 0);
      o1 = __builtin_amdgcn_mfma_f32_32x32x16_f16(pA0, v01, o1, 0, 0, 0);
      o0 = __builtin_amdgcn_mfma_f32_32x32x16_f16(pA1, v10, o0, 0, 0, 0);
      o1 = __builtin_amdgcn_mfma_f32_32x32x16_f16(pA1, v11, o1, 0, 0, 0);
      __builtin_amdgcn_s_setprio(0);
    }

    __syncthreads();  // fence + barrier + counter drain: next tile fully in LDS
  }

  // ---- epilogue: O reg r holds q-row (r&3)+8*(r>>2)+4*hi, d-col q (+0/32)
  const int b = bh >> 4, hh = bh & 15;
  float invl = 1.0f / lreg;
#pragma unroll
  for (int r = 0; r < 16; ++r) {
    int qrow = (r & 3) + 8 * (r >> 2) + 4 * hi;
    float inv = __shfl(invl, qrow);
    __half* orow = out + (size_t)(b * 2048 + q0 + w * 32 + qrow) * 1024 + hh * 64;
    orow[q] = __float2half(o0[r] * inv);
    orow[32 + q] = __float2half(o1[r] * inv);
  }
}

// ---------------- launch ----------------
extern "C" void kernel_launch(void* const* d_in, const int* in_sizes, int n_in,
                              void* d_out, int out_size, void* d_ws, size_t ws_size,
                              hipStream_t stream) {
  const float* x    = (const float*)d_in[0];  // [4,2048,1024]
  const float* rot  = (const float*)d_in[1];  // [2048,64]
  const float* wqkv = (const float*)d_in[2];  // [3072,1024]
  const float* wout = (const float*)d_in[3];  // [1024,1024]
  float* out = (float*)d_out;
  char* ws = (char*)d_ws;

  __half* xb    = (__half*)(ws + 0);               // 16 MB (A input, live through gemm1)
  __half* wqkvb = (__half*)(ws + (16ull << 20));   // 6 MB
  __half* woutb = (__half*)(ws + (22ull << 20));   // 2 MB
  __half* qr    = (__half*)(ws + (24ull << 20));   // 16 MB (must NOT alias xb)
  __half* ao    = (__half*)(ws + (40ull << 20));   // 16 MB
  __half* kr    = (__half*)(ws + (72ull << 20));   // 16 MB
  __half* vr    = (__half*)(ws + (88ull << 20));   // 16 MB (TRANSPOSED [bh][d][n])

  // one fused convert for x, wqkv, wout (1572864 groups = 6144 * 256)
  cvt3_f32_f16<<<6144, 256, 0, stream>>>(x, wqkv, wout, xb, wqkvb, woutb);
  // fused: qkv-proj + RoPE + head-scatter -> qr, kr, vr (256x128 tile, 512 thr)
  gemm_qkv_rope<<<dim3(24, 32), 512, 0, stream>>>(xb, wqkvb, rot, qr, kr, vr);
  attn_fwd<<<1024, 256, 0, stream>>>(qr, kr, vr, ao);
  // out = ao @ woutb^T   [8192,1024] f32
  gemm_bt_f32<<<dim3(8, 64), 256, 0, stream>>>(ao, woutb, out, 1024, 1024);
}

// Round 18
// 212.173 us; speedup vs baseline: 1.0712x; 1.0712x over previous
//
#include <hip/hip_runtime.h>
#include <hip/hip_fp16.h>
#include <stdint.h>

#define DEVI __device__ __forceinline__

using f16x2 = __attribute__((ext_vector_type(2))) _Float16;
using f16x8 = __attribute__((ext_vector_type(8))) _Float16;
using f32x4 = __attribute__((ext_vector_type(4))) float;
using f32x16 = __attribute__((ext_vector_type(16))) float;
using u32x4 = __attribute__((ext_vector_type(4))) uint32_t;

// global -> LDS direct copy, 16B per lane. LDS dest is wave-uniform base;
// HW writes base + lane*16 (guide m104/m108). Global src is per-lane.
DEVI void gload_lds16(const void* g, void* lds) {
  using GP = const __attribute__((address_space(1))) void*;
  using LP = __attribute__((address_space(3))) void*;
  __builtin_amdgcn_global_load_lds((GP)g, (LP)lds, 16, 0, 0);
}

DEVI uint32_t pack2h(float a, float b) {
  return (uint32_t)__half_as_ushort(__float2half(a)) |
         ((uint32_t)__half_as_ushort(__float2half(b)) << 16);
}

DEVI uint32_t cvtpk(float a, float b) {  // v_cvt_pkrtz_f16_f32
  auto h2 = __builtin_amdgcn_cvt_pkrtz(a, b);
  return __builtin_bit_cast(uint32_t, h2);
}

DEVI void plswap(uint32_t& a, uint32_t& b) {  // v_permlane32_swap_b32 (distinct values only)
  asm volatile("v_permlane32_swap_b32 %0, %1" : "+v"(a), "+v"(b));
}

DEVI float dot2acc(uint32_t w, f16x2 one, float c) {  // v_dot2_f32_f16
  return __builtin_amdgcn_fdot2(__builtin_bit_cast(f16x2, w), one, c, false);
}

DEVI float fmax3(float a, float b, float c) { return fmaxf(fmaxf(a, b), c); }

// ---------------- fused f32 -> f16 convert for all three inputs ----------------
// x: 1048576 groups, wqkv: 393216, wout: 131072; total 1572864 = 6144 * 256.
__global__ __launch_bounds__(256) void cvt3_f32_f16(const float* __restrict__ x,
                                                    const float* __restrict__ wq,
                                                    const float* __restrict__ wo,
                                                    __half* __restrict__ xb,
                                                    __half* __restrict__ wqb,
                                                    __half* __restrict__ wob) {
  int i = blockIdx.x * 256 + threadIdx.x;
  const float* in;
  __half* out;
  int j;
  if (i < 1048576) {
    in = x; out = xb; j = i;
  } else if (i < 1048576 + 393216) {
    in = wq; out = wqb; j = i - 1048576;
  } else {
    in = wo; out = wob; j = i - 1441792;
  }
  float4 a = ((const float4*)in)[j * 2];
  float4 b = ((const float4*)in)[j * 2 + 1];
  uint4 u;
  u.x = pack2h(a.x, a.y);
  u.y = pack2h(a.z, a.w);
  u.z = pack2h(b.x, b.y);
  u.w = pack2h(b.z, b.w);
  ((uint4*)out)[j] = u;
}

// ================= shared GEMM core (128x128 tile, BK=64, proven R11/R12) ==========
// staging swizzle: 128B rows, 16B slot ^= row&7; read: conflict-free per half.
// Takes explicit (bx, by) so callers can XCD-swizzle the block index.
#define GEMM_CORE(A_, B_, K_, BX_, BY_)                                                 \
  __shared__ __half As[128 * 64];                                                       \
  __shared__ __half Bs[128 * 64];                                                       \
  const int tid = threadIdx.x;                                                          \
  const int w = tid >> 6, l = tid & 63;                                                 \
  const int wm = w >> 1, wn = w & 1;                                                    \
  const int m16 = l & 15, g = l >> 4;                                                   \
  const int row0 = (BY_)*128, col0 = (BX_)*128;                                         \
  const int srow = l >> 3;                                                              \
  const int ks = ((l & 7) ^ srow) * 8;                                                  \
  f32x4 acc[4][4] = {};                                                                 \
  for (int kt = 0; kt < (K_); kt += 64) {                                               \
    __syncthreads();                                                                    \
    _Pragma("unroll") for (int i = 0; i < 4; ++i) {                                     \
      int c = w * 4 + i;                                                                \
      int r = c * 8 + srow;                                                             \
      gload_lds16((A_) + (size_t)(row0 + r) * (K_) + kt + ks, (char*)As + c * 1024);    \
      gload_lds16((B_) + (size_t)(col0 + r) * (K_) + kt + ks, (char*)Bs + c * 1024);    \
    }                                                                                   \
    __syncthreads();                                                                    \
    _Pragma("unroll") for (int kk = 0; kk < 2; ++kk) {                                  \
      f16x8 aF[4], bF[4];                                                               \
      _Pragma("unroll") for (int mi = 0; mi < 4; ++mi) {                                \
        int r = wm * 64 + mi * 16 + m16;                                                \
        aF[mi] = *(const f16x8*)((const char*)As + r * 128 + (((kk * 4 + g) ^ (r & 7)) << 4)); \
      }                                                                                 \
      _Pragma("unroll") for (int ni = 0; ni < 4; ++ni) {                                \
        int r = wn * 64 + ni * 16 + m16;                                                \
        bF[ni] = *(const f16x8*)((const char*)Bs + r * 128 + (((kk * 4 + g) ^ (r & 7)) << 4)); \
      }                                                                                 \
      _Pragma("unroll") for (int mi = 0; mi < 4; ++mi)                                  \
          _Pragma("unroll") for (int ni = 0; ni < 4; ++ni)                              \
              acc[mi][ni] = __builtin_amdgcn_mfma_f32_16x16x32_f16(aF[mi], bF[ni],      \
                                                                   acc[mi][ni], 0, 0, 0); \
    }                                                                                   \
  }

// ---------------- GEMM + fused RoPE/scatter (produces qr, kr, vr directly) ----------
// XCD-swizzled block index (y-chunked; 1536 % 8 == 0 -> bijective). Proven R14.
__global__ __launch_bounds__(256) void gemm_qkv_rope(const __half* __restrict__ A,
                                                     const __half* __restrict__ B,
                                                     const float* __restrict__ rot,
                                                     __half* __restrict__ qr,
                                                     __half* __restrict__ kr,
                                                     __half* __restrict__ vr) {
  const int id = blockIdx.y * 24 + blockIdx.x;        // 1536 blocks
  const int nid = (id & 7) * 192 + (id >> 3);         // XCD swizzle (bijective)
  const int bx = nid % 24, by = nid / 24;

  GEMM_CORE(A, B, 1024, bx, by)

  const int s = bx >> 3;                  // 0=q, 1=k, 2=v
  const int hh = (bx & 7) * 2 + wn;       // this wave's head
  if (s < 2) {
    const float sc = (s == 0) ? 0.18033688011112042f : 1.0f;  // log2(e)/sqrt(64)
    __half* base = (s == 0) ? qr : kr;
#pragma unroll
    for (int mi = 0; mi < 4; ++mi)
#pragma unroll
      for (int j = 0; j < 4; ++j) {
        int r = row0 + wm * 64 + mi * 16 + g * 4 + j;  // global row = b*2048+n
        int n = r & 2047;
        int bh = (r >> 11) * 16 + hh;
        __half* orow = base + ((size_t)bh * 2048 + n) * 64;
        const float* rp = rot + n * 64;
#pragma unroll
        for (int ni = 0; ni < 2; ++ni) {
          int dlo = ni * 16 + m16;
          float xlo = acc[mi][ni][j], xhi = acc[mi][ni + 2][j];
          float s0, c0, s1, c1;
          __sincosf(rp[dlo], &s0, &c0);
          __sincosf(rp[dlo + 32], &s1, &c1);
          orow[dlo]      = __float2half((xlo * c0 - xhi * s0) * sc);
          orow[dlo + 32] = __float2half((xhi * c1 + xlo * s1) * sc);
        }
      }
  } else {
#pragma unroll
    for (int mi = 0; mi < 4; ++mi)
#pragma unroll
      for (int j = 0; j < 4; ++j) {
        int r = row0 + wm * 64 + mi * 16 + g * 4 + j;
        int n = r & 2047;
        int bh = (r >> 11) * 16 + hh;
        __half* vcol = vr + ((size_t)bh * 64) * 2048 + n;
#pragma unroll
        for (int ni = 0; ni < 4; ++ni) {
          int d = ni * 16 + m16;
          vcol[(size_t)d * 2048] = __float2half(acc[mi][ni][j]);
        }
      }
  }
}

// ---------------- plain GEMM (out-proj), 128x128, f32 output, XCD-swizzled --------
__global__ __launch_bounds__(256) void gemm_bt_f32(const __half* __restrict__ A,
                                                   const __half* __restrict__ B,
                                                   float* __restrict__ C, int N, int K) {
  const int id = blockIdx.y * 8 + blockIdx.x;         // 512 blocks
  const int nid = (id & 7) * 64 + (id >> 3);          // XCD swizzle (bijective)
  const int bx = nid % 8, by = nid / 8;

  GEMM_CORE(A, B, K, bx, by)
#pragma unroll
  for (int mi = 0; mi < 4; ++mi)
#pragma unroll
    for (int ni = 0; ni < 4; ++ni)
#pragma unroll
      for (int j = 0; j < 4; ++j) {
        int r = row0 + wm * 64 + mi * 16 + g * 4 + j;
        int cc = col0 + wn * 64 + ni * 16 + m16;
        C[(size_t)r * N + cc] = acc[mi][ni][j];
      }
}

// ---------------- Flash attention fwd, swapped-QK 32x32 (EXACT R14 version) --------
__global__ __launch_bounds__(256, 4) void attn_fwd(const __half* __restrict__ qr,
                                                   const __half* __restrict__ kr,
                                                   const __half* __restrict__ vr,
                                                   __half* __restrict__ out) {
  __shared__ __half K2[2 * 64 * 64];  // 16 KB
  __shared__ __half V2[2 * 64 * 64];  // 16 KB

  int bid = blockIdx.x;
  bid = (bid & 7) * 128 + (bid >> 3);  // XCD swizzle: same-head blocks share an XCD L2
  const int bh = bid >> 4;
  const int q0 = (bid & 15) * 128;
  const int tid = threadIdx.x;
  const int w = tid >> 6, l = tid & 63;
  const int q = l & 31, hi = l >> 5;
  const size_t headoff = (size_t)bh * 2048 * 64;

  // Q B-frags: Q[q0+w*32+q][c*16 + hi*8 .. +7], c=0..3 (held all block)
  f16x8 qB[4];
  {
    const __half* qp = qr + headoff + (size_t)(q0 + w * 32 + q) * 64 + hi * 8;
#pragma unroll
    for (int c = 0; c < 4; ++c) qB[c] = *(const f16x8*)(qp + c * 16);
  }

  // hoisted lane-invariant LDS read offsets
  int kf[4];  // K A-frag: byte = Kb + kvb*4096 + kf[c]   (kvb in {0,1})
#pragma unroll
  for (int c = 0; c < 4; ++c)
    kf[c] = q * 128 + 16 * (hi ^ (q & 1)) + 32 * (c ^ ((q >> 1) & 3));
  // V B-frag: byte = Vb + (vbase ^ (kvb<<6) [^32 hi16]) [+4096 for d1]
  const int vbase = q * 128 + ((hi ^ (q & 7)) << 4);

  // staging coords
  const int krow_l = l >> 3, kslot = l & 7;
  const __half* kb = kr + headoff;
  const __half* vb = vr + (size_t)bh * 64 * 2048;

  auto STAGE = [&](int buf, int kv0) {
#pragma unroll
    for (int i = 0; i < 2; ++i) {  // K [64 kv][64 d], slot ^= kv&7
      int c = w * 2 + i;
      int row = c * 8 + krow_l;
      gload_lds16(kb + (size_t)(kv0 + row) * 64 + ((kslot ^ (row & 7)) * 8),
                  (char*)K2 + buf * 8192 + c * 1024);
    }
#pragma unroll
    for (int i = 0; i < 2; ++i) {  // V [64 d][64 kv], slot ^= d&7
      int c = w * 2 + i;
      int d = c * 8 + (l >> 3);
      gload_lds16(vb + (size_t)d * 2048 + kv0 + (((l & 7) ^ (l >> 3)) * 8),
                  (char*)V2 + buf * 8192 + c * 1024);
    }
  };

  const f16x2 one2 = {(_Float16)1.f, (_Float16)1.f};
  f32x16 o0 = {}, o1 = {};  // O[q-rows][d0=q / d1=q+32]
  float mreg = -1e30f, lreg = 0.f;

  STAGE(0, 0);
  __syncthreads();

  for (int t = 0; t < 32; ++t) {
    const int buf = t & 1;
    if (t < 31) STAGE(buf ^ 1, (t + 1) * 64);  // prefetch next tile (overlaps compute)

    const char* Kb = (const char*)K2 + buf * 8192;
    const char* Vb = (const char*)V2 + buf * 8192;
#pragma unroll
    for (int kvb = 0; kvb < 2; ++kvb) {
      // ---- S^T[kv 32][q 32] = K * Q^T
      f32x16 s = {};
      __builtin_amdgcn_s_setprio(1);
#pragma unroll
      for (int c = 0; c < 4; ++c) {
        f16x8 kA = *(const f16x8*)(Kb + kvb * 4096 + kf[c]);
        s = __builtin_amdgcn_mfma_f32_32x32x16_f16(kA, qB[c], s, 0, 0, 0);
      }
      __builtin_amdgcn_s_setprio(0);

      // ---- in-register online softmax (lane owns q-col l&31, 16 kv rows)
      float mt = fmax3(s[0], s[1], s[2]);
      mt = fmax3(mt, s[3], s[4]);
      mt = fmax3(mt, s[5], s[6]);
      mt = fmax3(mt, s[7], s[8]);
      mt = fmax3(mt, s[9], s[10]);
      mt = fmax3(mt, s[11], s[12]);
      mt = fmax3(mt, s[13], s[14]);
      mt = fmaxf(mt, s[15]);
      mt = fmaxf(mt, __shfl_xor(mt, 32));
      if (__any(mt - mreg > 8.f)) {  // defer-max (T13)
        float mnew = fmaxf(mreg, mt);
        float alpha = __builtin_amdgcn_exp2f(mreg - mnew);
        lreg *= alpha;
        o0 *= alpha;
        o1 *= alpha;
        mreg = mnew;
      }
      uint32_t W[8];
      float rs = 0.f;
#pragma unroll
      for (int i2 = 0; i2 < 8; ++i2) {  // exp2 + pack + fused row-sum (fdot2)
        float e0 = __builtin_amdgcn_exp2f(s[2 * i2] - mreg);
        float e1 = __builtin_amdgcn_exp2f(s[2 * i2 + 1] - mreg);
        W[i2] = cvtpk(e0, e1);
        rs = dot2acc(W[i2], one2, rs);
      }
      rs += __shfl_xor(rs, 32);
      lreg += rs;

      // ---- P-frag redistribution: 4 permlane32_swap (proven)
      plswap(W[0], W[2]);
      plswap(W[1], W[3]);
      plswap(W[4], W[6]);
      plswap(W[5], W[7]);
      u32x4 f0 = {W[0], W[1], W[2], W[3]};
      u32x4 f1 = {W[4], W[5], W[6], W[7]};
      f16x8 pA0 = __builtin_bit_cast(f16x8, f0);  // kv kvb*32 + 0..15
      f16x8 pA1 = __builtin_bit_cast(f16x8, f1);  // kv kvb*32 + 16..31

      // ---- PV: O += P * V   (V reads from 128B-row layout)
      const int vx = vbase ^ (kvb << 6);   // kv lo-16 slot
      const int vx2 = vx ^ 32;             // kv hi-16 slot
      f16x8 v00 = *(const f16x8*)(Vb + vx);
      f16x8 v01 = *(const f16x8*)(Vb + vx + 4096);
      f16x8 v10 = *(const f16x8*)(Vb + vx2);
      f16x8 v11 = *(const f16x8*)(Vb + vx2 + 4096);
      __builtin_amdgcn_s_setprio(1);
      o0 = __builtin_amdgcn_mfma_f32_32x32x16_f16(pA0, v00, o0, 0, 0, 0);
      o1 = __builtin_amdgcn_mfma_f32_32x32x16_f16(pA0, v01, o1, 0, 0, 0);
      o0 = __builtin_amdgcn_mfma_f32_32x32x16_f16(pA1, v10, o0, 0, 0, 0);
      o1 = __builtin_amdgcn_mfma_f32_32x32x16_f16(pA1, v11, o1, 0, 0, 0);
      __builtin_amdgcn_s_setprio(0);
    }

    __syncthreads();  // fence + barrier + counter drain: next tile fully in LDS
  }

  // ---- epilogue: O reg r holds q-row (r&3)+8*(r>>2)+4*hi, d-col q (+0/32)
  const int b = bh >> 4, hh = bh & 15;
  float invl = 1.0f / lreg;
#pragma unroll
  for (int r = 0; r < 16; ++r) {
    int qrow = (r & 3) + 8 * (r >> 2) + 4 * hi;
    float inv = __shfl(invl, qrow);
    __half* orow = out + (size_t)(b * 2048 + q0 + w * 32 + qrow) * 1024 + hh * 64;
    orow[q] = __float2half(o0[r] * inv);
    orow[32 + q] = __float2half(o1[r] * inv);
  }
}

// ---------------- launch ----------------
extern "C" void kernel_launch(void* const* d_in, const int* in_sizes, int n_in,
                              void* d_out, int out_size, void* d_ws, size_t ws_size,
                              hipStream_t stream) {
  const float* x    = (const float*)d_in[0];  // [4,2048,1024]
  const float* rot  = (const float*)d_in[1];  // [2048,64]
  const float* wqkv = (const float*)d_in[2];  // [3072,1024]
  const float* wout = (const float*)d_in[3];  // [1024,1024]
  float* out = (float*)d_out;
  char* ws = (char*)d_ws;

  __half* xb    = (__half*)(ws + 0);               // 16 MB (A input, live through gemm1)
  __half* wqkvb = (__half*)(ws + (16ull << 20));   // 6 MB
  __half* woutb = (__half*)(ws + (22ull << 20));   // 2 MB
  __half* qr    = (__half*)(ws + (24ull << 20));   // 16 MB (must NOT alias xb)
  __half* ao    = (__half*)(ws + (40ull << 20));   // 16 MB
  __half* kr    = (__half*)(ws + (72ull << 20));   // 16 MB
  __half* vr    = (__half*)(ws + (88ull << 20));   // 16 MB (TRANSPOSED [bh][d][n])

  // one fused convert for x, wqkv, wout (1572864 groups = 6144 * 256)
  cvt3_f32_f16<<<6144, 256, 0, stream>>>(x, wqkv, wout, xb, wqkvb, woutb);
  // fused: qkv-proj + RoPE + head-scatter -> qr, kr, vr (no qkv intermediate)
  gemm_qkv_rope<<<dim3(24, 64), 256, 0, stream>>>(xb, wqkvb, rot, qr, kr, vr);
  attn_fwd<<<1024, 256, 0, stream>>>(qr, kr, vr, ao);
  // out = ao @ woutb^T   [8192,1024] f32
  gemm_bt_f32<<<dim3(8, 64), 256, 0, stream>>>(ao, woutb, out, 1024, 1024);
}